// Round 2
// baseline (956.678 us; speedup 1.0000x reference)
//
#include <hip/hip_runtime.h>
#include <hip/hip_bf16.h>
#include <stdint.h>

typedef __bf16 bf16_t;
typedef __bf16 bf16x8 __attribute__((ext_vector_type(8)));
typedef float f32x4 __attribute__((ext_vector_type(4)));

#define B_SZ   8192
#define D_IN   1024
#define D_HID  2048
#define D_OUT  1024

__device__ __forceinline__ float sigm(float x) { return 1.0f / (1.0f + __expf(-x)); }

// ---------------- multi-tensor f32 -> bf16 cast ----------------
struct CastJobs {
  const float* src[9];
  bf16_t* dst[9];
  int n8[9];
};

__global__ __launch_bounds__(256) void cast_kernel(CastJobs j) {
  const int which = blockIdx.y;
  const int t = blockIdx.x * 256 + threadIdx.x;
  if (t >= j.n8[which]) return;
  const float4* s = (const float4*)j.src[which];
  float4 a = s[2 * t], b = s[2 * t + 1];
  bf16x8 o;
  o[0] = (bf16_t)a.x; o[1] = (bf16_t)a.y; o[2] = (bf16_t)a.z; o[3] = (bf16_t)a.w;
  o[4] = (bf16_t)b.x; o[5] = (bf16_t)b.y; o[6] = (bf16_t)b.z; o[7] = (bf16_t)b.w;
  *(bf16x8*)(j.dst[which] + (size_t)t * 8) = o;
}

// =====================================================================
// 256x256 8-phase GEMM (T2 swizzle + T3/T4 counted vmcnt + T5 setprio)
// MODE 0: stacked gates (r: K=3072, z: K=3072, hx: K=1024), epilogue fuses
//         sigmoid / rh / hx+bias.  MODE 1: rh@Whh^T, epilogue fuses
//         tanh + blend -> out_nh(f32) + nhb(bf16).
// 8 waves (2M x 4N); per phase: one C-quadrant (mh,nh), 16 MFMA.
// LDS 128 KiB = {A,B} x dbuf2 x half2 x [128][64] bf16, XOR-swizzled
// (linear global_load_lds dest + inverse-swizzled global source).
// Half-tile prefetch schedule (phase j of tile t):
//   j0: B-h0(t+1)   j1: A-h1(t+1)   j2: A-h0(t+2)   j3: B-h1(t+2)
// One s_waitcnt vmcnt(4) per K-tile (at j3) => all of tile t+1 landed,
// the 2 newest half-tiles may remain in flight.
// =====================================================================
template <int MODE>
__global__ __launch_bounds__(512, 2) void gru_gemm8(
    const bf16_t* __restrict__ xb, const bf16_t* __restrict__ hb,
    const bf16_t* __restrict__ wxr, const bf16_t* __restrict__ whr,
    const bf16_t* __restrict__ wxz, const bf16_t* __restrict__ whz,
    const bf16_t* __restrict__ wxh, const bf16_t* __restrict__ whh,
    const float* __restrict__ bxr, const float* __restrict__ bxz,
    const float* __restrict__ bxh,
    const float* __restrict__ hidden_f32,
    bf16_t* __restrict__ rh, bf16_t* __restrict__ zb, bf16_t* __restrict__ hx,
    bf16_t* __restrict__ nhb, float* __restrict__ out_nh) {
  __shared__ char lds[131072];

  const int tid = threadIdx.x;
  const int wid = tid >> 6, lane = tid & 63;
  const int wr = wid >> 2, wc = wid & 3;
  const int l15 = lane & 15, lq = lane >> 4;

  // XCD-aware bijective swizzle (nwg % 8 == 0 in both modes)
  const int nbx = 32;
  const int nby = (MODE == 0) ? 24 : 8;
  const int nwg = nbx * nby;
  int flat = blockIdx.y * nbx + blockIdx.x;
  flat = (flat & 7) * (nwg >> 3) + (flat >> 3);
  const int bx = flat & 31, by = flat >> 5;
  const int bm = bx * 256;
  int region = 0, bn;
  if (MODE == 0) { region = by >> 3; bn = (by & 7) * 256; }
  else bn = by * 256;

  const int NT = (MODE == 0) ? (region == 2 ? 16 : 48) : 32;

  auto srcA = [&](int t, const bf16_t*& p, int& ld, int& col) {
    int kt = t * 64;
    if (MODE == 0) {
      if (kt < D_IN) { p = xb; ld = D_IN; col = kt; }
      else { p = hb; ld = D_HID; col = kt - D_IN; }
    } else { p = rh; ld = D_HID; col = kt; }
  };
  auto srcB = [&](int t, const bf16_t*& p, int& ld, int& col) {
    int kt = t * 64;
    if (MODE == 0) {
      const bf16_t* BX = (region == 0) ? wxr : (region == 1) ? wxz : wxh;
      if (region == 2 || kt < D_IN) { p = BX; ld = D_IN; col = kt; }
      else { p = (region == 0) ? whr : whz; ld = D_HID; col = kt - D_IN; }
    } else { p = whh; ld = D_HID; col = kt; }
  };

  auto stage = [&](const bf16_t* p, int ld, int rowbase, int col, char* ldsbase) {
#pragma unroll
    for (int i = 0; i < 2; ++i) {
      int pp = i * 8192 + wid * 1024 + lane * 16;
      int row = pp >> 7;
      int chunk = ((pp >> 4) & 7) ^ (row & 7);   // inverse-swizzled source
      const bf16_t* g = p + (size_t)(rowbase + row) * ld + col + chunk * 8;
      __builtin_amdgcn_global_load_lds(
          (const __attribute__((address_space(1))) void*)g,
          (__attribute__((address_space(3))) void*)(ldsbase + i * 8192 + wid * 1024),
          16, 0, 0);
    }
  };
  auto stageA = [&](int t, int half) {
    const bf16_t* p; int ld, col; srcA(t, p, ld, col);
    stage(p, ld, bm + half * 128, col, lds + (t & 1) * 32768 + half * 16384);
  };
  auto stageB = [&](int t, int half) {
    const bf16_t* p; int ld, col; srcB(t, p, ld, col);
    stage(p, ld, bn + half * 128, col, lds + 65536 + (t & 1) * 32768 + half * 16384);
  };

  auto readA = [&](int cur, int mh, int mi, int ks) {
    int row = wr * 64 + mi * 16 + l15;
    int chunk = (ks * 4 + lq) ^ (l15 & 7);       // matching read-side swizzle
    return *(const bf16x8*)(lds + cur * 32768 + mh * 16384 + row * 128 + chunk * 16);
  };
  auto readB = [&](int cur, int nh, int ni, int ks) {
    int row = wc * 32 + ni * 16 + l15;
    int chunk = (ks * 4 + lq) ^ (l15 & 7);
    return *(const bf16x8*)(lds + 65536 + cur * 32768 + nh * 16384 + row * 128 + chunk * 16);
  };

  f32x4 acc[4][4][2];   // [quadrant j][mi][ni]
#pragma unroll
  for (int j = 0; j < 4; ++j)
#pragma unroll
    for (int mi = 0; mi < 4; ++mi)
#pragma unroll
      for (int ni = 0; ni < 2; ++ni) acc[j][mi][ni] = (f32x4){0.f, 0.f, 0.f, 0.f};

  bf16x8 af[4][2], bfr[2][2];

  // prologue: tile0 fully + the two long-lead halves of tile1
  stageA(0, 0); stageB(0, 0); stageA(0, 1); stageB(0, 1);
  if (NT > 1) { stageA(1, 0); stageB(1, 1); }
  asm volatile("s_waitcnt vmcnt(4)" ::: "memory");
  __builtin_amdgcn_s_barrier();

  for (int t = 0; t < NT; ++t) {
    const int cur = t & 1;
#define GRU_PHASE(J, MH, NH, LA, LB, STG)                                   \
    {                                                                        \
      if (LA) {                                                              \
        _Pragma("unroll") for (int mi = 0; mi < 4; ++mi)                     \
        _Pragma("unroll") for (int ks = 0; ks < 2; ++ks)                     \
          af[mi][ks] = readA(cur, MH, mi, ks);                               \
      }                                                                      \
      if (LB) {                                                              \
        _Pragma("unroll") for (int ni = 0; ni < 2; ++ni)                     \
        _Pragma("unroll") for (int ks = 0; ks < 2; ++ks)                     \
          bfr[ni][ks] = readB(cur, NH, ni, ks);                              \
      }                                                                      \
      STG;                                                                   \
      __builtin_amdgcn_s_barrier();                                          \
      asm volatile("s_waitcnt lgkmcnt(0)" ::: "memory");                     \
      __builtin_amdgcn_s_setprio(1);                                         \
      _Pragma("unroll") for (int mi = 0; mi < 4; ++mi)                       \
      _Pragma("unroll") for (int ni = 0; ni < 2; ++ni)                       \
      _Pragma("unroll") for (int ks = 0; ks < 2; ++ks)                       \
        acc[J][mi][ni] = __builtin_amdgcn_mfma_f32_16x16x32_bf16(            \
            af[mi][ks], bfr[ni][ks], acc[J][mi][ni], 0, 0, 0);               \
      __builtin_amdgcn_s_setprio(0);                                         \
      if (J == 3) { asm volatile("s_waitcnt vmcnt(4)" ::: "memory"); }       \
      __builtin_amdgcn_s_barrier();                                          \
    }

    GRU_PHASE(0, 0, 0, true,  true,  { if (t + 1 < NT) stageB(t + 1, 0); })
    GRU_PHASE(1, 0, 1, false, true,  { if (t + 1 < NT) stageA(t + 1, 1); })
    GRU_PHASE(2, 1, 1, true,  false, { if (t + 2 < NT) stageA(t + 2, 0); })
    GRU_PHASE(3, 1, 0, false, true,  { if (t + 2 < NT) stageB(t + 2, 1); })
#undef GRU_PHASE
  }

  // ---------------- fused epilogue ----------------
#pragma unroll
  for (int j = 0; j < 4; ++j) {
    const int mh = (j >= 2) ? 1 : 0;
    const int nh = (j == 1 || j == 2) ? 1 : 0;
#pragma unroll
    for (int ni = 0; ni < 2; ++ni) {
      const int col = bn + nh * 128 + wc * 32 + ni * 16 + l15;
#pragma unroll
      for (int mi = 0; mi < 4; ++mi) {
        const int row0 = bm + mh * 128 + wr * 64 + mi * 16 + lq * 4;
#pragma unroll
        for (int r = 0; r < 4; ++r) {
          const int row = row0 + r;
          const float v = acc[j][mi][ni][r];
          const size_t off = (size_t)row * D_HID + col;
          if (MODE == 0) {
            if (region == 0) {
              float rr = sigm(v + bxr[col]);
              rh[off] = (bf16_t)(rr * hidden_f32[off]);
            } else if (region == 1) {
              zb[off] = (bf16_t)sigm(v + bxz[col]);
            } else {
              hx[off] = (bf16_t)(v + bxh[col]);
            }
          } else {
            float hc = tanhf((float)hx[off] + v);
            float z = (float)zb[off];
            float h = hidden_f32[off];
            float nh2 = z * h + (1.0f - z) * hc;
            out_nh[off] = nh2;
            nhb[off] = (bf16_t)nh2;
          }
        }
      }
    }
  }
}

// =====================================================================
// 128x128 2-barrier kernel, kept for MODE 2 (out = nhb @ Who^T + b):
// only 34 GF and N=1024 would give 128 blocks at 256^2 (half the chip idle).
// =====================================================================
__global__ __launch_bounds__(256, 2) void gru_gemm_out(
    const bf16_t* __restrict__ nhb, const bf16_t* __restrict__ who,
    const float* __restrict__ bwo, float* __restrict__ out_y) {
  __shared__ char lds[32768];
  char* sA = lds;
  char* sB = lds + 16384;

  const int tid = threadIdx.x;
  const int wid = tid >> 6;
  const int lane = tid & 63;
  const int wr = wid >> 1, wc = wid & 1;
  const int l15 = lane & 15, lq = lane >> 4;

  const int bm = blockIdx.x * 128;
  const int bn = blockIdx.y * 128;

  f32x4 acc[4][4];
#pragma unroll
  for (int i = 0; i < 4; ++i)
#pragma unroll
    for (int j = 0; j < 4; ++j) acc[i][j] = (f32x4){0.f, 0.f, 0.f, 0.f};

  auto stage_tile = [&](const bf16_t* src, int ld, int row_base, int col_base, char* tile) {
#pragma unroll
    for (int i = 0; i < 4; ++i) {
      int p = i * 4096 + wid * 1024 + lane * 16;
      int row = p >> 7;
      int chunk = ((p >> 4) & 7) ^ (row & 7);
      const bf16_t* g = src + (size_t)(row_base + row) * ld + col_base + chunk * 8;
      __builtin_amdgcn_global_load_lds(
          (const __attribute__((address_space(1))) void*)g,
          (__attribute__((address_space(3))) void*)(tile + i * 4096 + wid * 1024),
          16, 0, 0);
    }
  };
  auto read_frag = [&](const char* tile, int row, int k) {
    int slot = (k >> 3) ^ (row & 7);
    return *(const bf16x8*)(tile + row * 128 + slot * 16);
  };

  for (int kt = 0; kt < D_HID; kt += 64) {
    stage_tile(nhb, D_HID, bm, kt, sA);
    stage_tile(who, D_HID, bn, kt, sB);
    asm volatile("s_waitcnt vmcnt(0)" ::: "memory");
    __syncthreads();

#pragma unroll
    for (int kk = 0; kk < 64; kk += 32) {
      bf16x8 af[4], bfv[4];
      const int k = kk + lq * 8;
#pragma unroll
      for (int i = 0; i < 4; ++i) af[i]  = read_frag(sA, wr * 64 + i * 16 + l15, k);
#pragma unroll
      for (int i = 0; i < 4; ++i) bfv[i] = read_frag(sB, wc * 64 + i * 16 + l15, k);
#pragma unroll
      for (int mi = 0; mi < 4; ++mi)
#pragma unroll
        for (int ni = 0; ni < 4; ++ni)
          acc[mi][ni] = __builtin_amdgcn_mfma_f32_16x16x32_bf16(af[mi], bfv[ni], acc[mi][ni], 0, 0, 0);
    }
    __syncthreads();
  }

#pragma unroll
  for (int ni = 0; ni < 4; ++ni) {
    const int col = bn + wc * 64 + ni * 16 + l15;
#pragma unroll
    for (int mi = 0; mi < 4; ++mi) {
      const int row0 = bm + wr * 64 + mi * 16 + lq * 4;
#pragma unroll
      for (int j = 0; j < 4; ++j)
        out_y[(size_t)(row0 + j) * D_OUT + col] = acc[mi][ni][j] + bwo[col];
    }
  }
}

// ---------------- host launcher ----------------
extern "C" void kernel_launch(void* const* d_in, const int* in_sizes, int n_in,
                              void* d_out, int out_size, void* d_ws, size_t ws_size,
                              hipStream_t stream) {
  const float* x   = (const float*)d_in[0];
  const float* hid = (const float*)d_in[1];
  const float* Wxr = (const float*)d_in[2];
  const float* bxr = (const float*)d_in[3];
  const float* Whr = (const float*)d_in[4];
  const float* Wxz = (const float*)d_in[5];
  const float* bxz = (const float*)d_in[6];
  const float* Whz = (const float*)d_in[7];
  const float* Wxh = (const float*)d_in[8];
  const float* bxh = (const float*)d_in[9];
  const float* Whh = (const float*)d_in[10];
  const float* Who = (const float*)d_in[11];
  const float* bwo = (const float*)d_in[12];

  float* out_y  = (float*)d_out;                     // (8192,1024)
  float* out_nh = out_y + (size_t)B_SZ * D_OUT;      // (8192,2048)

  char* w = (char*)d_ws;
  auto alloc = [&](size_t bytes) { char* p = w; w += (bytes + 255) & ~(size_t)255; return p; };

  bf16_t* xb  = (bf16_t*)alloc((size_t)B_SZ * D_IN * 2);
  bf16_t* hb  = (bf16_t*)alloc((size_t)B_SZ * D_HID * 2);
  bf16_t* wxr = (bf16_t*)alloc((size_t)D_HID * D_IN * 2);
  bf16_t* whr = (bf16_t*)alloc((size_t)D_HID * D_HID * 2);
  bf16_t* wxz = (bf16_t*)alloc((size_t)D_HID * D_IN * 2);
  bf16_t* whz = (bf16_t*)alloc((size_t)D_HID * D_HID * 2);
  bf16_t* wxh = (bf16_t*)alloc((size_t)D_HID * D_IN * 2);
  bf16_t* whh = (bf16_t*)alloc((size_t)D_HID * D_HID * 2);
  bf16_t* who = (bf16_t*)alloc((size_t)D_OUT * D_HID * 2);
  bf16_t* rh  = (bf16_t*)alloc((size_t)B_SZ * D_HID * 2);
  bf16_t* zb  = (bf16_t*)alloc((size_t)B_SZ * D_HID * 2);
  bf16_t* hx  = (bf16_t*)alloc((size_t)B_SZ * D_HID * 2);
  bf16_t* nhb = (bf16_t*)alloc((size_t)B_SZ * D_HID * 2);

  CastJobs cj;
  const float* srcs[9] = {x, hid, Wxr, Whr, Wxz, Whz, Wxh, Whh, Who};
  bf16_t* dsts[9]      = {xb, hb, wxr, whr, wxz, whz, wxh, whh, who};
  const int ns[9] = {B_SZ * D_IN, B_SZ * D_HID,
                     D_HID * D_IN, D_HID * D_HID,
                     D_HID * D_IN, D_HID * D_HID,
                     D_HID * D_IN, D_HID * D_HID,
                     D_OUT * D_HID};
  for (int i = 0; i < 9; ++i) { cj.src[i] = srcs[i]; cj.dst[i] = dsts[i]; cj.n8[i] = ns[i] / 8; }

  cast_kernel<<<dim3(8192, 9), dim3(256), 0, stream>>>(cj);

  gru_gemm8<0><<<dim3(32, 24), dim3(512), 0, stream>>>(
      xb, hb, wxr, whr, wxz, whz, wxh, whh,
      bxr, bxz, bxh, hid, rh, zb, hx, nhb, out_nh);
  gru_gemm8<1><<<dim3(32, 8), dim3(512), 0, stream>>>(
      xb, hb, wxr, whr, wxz, whz, wxh, whh,
      bxr, bxz, bxh, hid, rh, zb, hx, nhb, out_nh);
  gru_gemm_out<<<dim3(64, 8), dim3(256), 0, stream>>>(nhb, who, bwo, out_y);
}